// Round 20
// baseline (3838.985 us; speedup 1.0000x reference)
//
#include <hip/hip_runtime.h>

// ---------------- constants ----------------
#define BB 32
#define TPB 3684L        // tokens per batch element = T*N = 12*307
#define TT 12
#define NN 307
#define DM 176           // model dim
#define KP 192           // padded K for MFMA (176 -> 192)
#define FFD 256
#define NH 4
#define HD 44
#define NTILE 77         // ceil(307/4) node tiles for temporal attn
#define TS 584           // temporal LDS per-(node,plane) stride (12*48 + 8 pad)
#define MLS 264          // ffn mid LDS row stride (elems): 16B-aligned rows, dw%32=4

typedef __bf16 bfv8 __attribute__((ext_vector_type(8)));
typedef float f32x4 __attribute__((ext_vector_type(4)));
typedef short sv4 __attribute__((ext_vector_type(4)));
typedef unsigned int uiv4 __attribute__((ext_vector_type(4)));
typedef unsigned long long ull;

__device__ __forceinline__ float b2f(unsigned short h) {
  return __uint_as_float(((unsigned)h) << 16);
}
__device__ __forceinline__ unsigned short f2b(float f) {
  unsigned u = __float_as_uint(f);
  return (unsigned short)((u + 0x7FFFu + ((u >> 16) & 1u)) >> 16);  // RNE
}

// MFMA 16x16x16 bf16 wrapper (builtin if present; asm fallback with hazard nops)
__device__ __forceinline__ f32x4 mfma16x16x16bf(sv4 a, sv4 b, f32x4 c) {
#if __has_builtin(__builtin_amdgcn_mfma_f32_16x16x16bf16_1k)
  return __builtin_amdgcn_mfma_f32_16x16x16bf16_1k(a, b, c, 0, 0, 0);
#else
  f32x4 d = c;
  asm("v_mfma_f32_16x16x16_bf16 %0, %1, %2, %0\n\ts_nop 7\n\ts_nop 7"
      : "+v"(d) : "v"(a), "v"(b));
  return d;
#endif
}

// ---------------- weight prep: transpose + bf16 + K-pad ----------------
//   Wqkv_t [528][192] @ 0        (101376)
//   Wo_t   [176][192] @ 101376   (33792)  rows permuted to k' = 48h + d (pad=0)
//   W1_t   [256][192] @ 135168   (49152)
//   W2_t   [176][256] @ 184320   (45056)
__global__ void prep_weights(
    const float* __restrict__ tWq, const float* __restrict__ tWk,
    const float* __restrict__ tWv, const float* __restrict__ tWo,
    const float* __restrict__ tW1, const float* __restrict__ tW2,
    const float* __restrict__ sWq, const float* __restrict__ sWk,
    const float* __restrict__ sWv, const float* __restrict__ sWo,
    const float* __restrict__ sW1, const float* __restrict__ sW2,
    const float* __restrict__ tbq, const float* __restrict__ tbk,
    const float* __restrict__ tbv,
    const float* __restrict__ sbq, const float* __restrict__ sbk,
    const float* __restrict__ sbv,
    unsigned short* __restrict__ wbase, float* __restrict__ bqkv) {
  int layer = blockIdx.y;       // 0..5
  int mat = blockIdx.z;         // 0..3
  int li = layer % 3;
  bool tp = (layer < 3);
  unsigned short* dst = wbase + (long)layer * 229376;
  long idx = (long)blockIdx.x * 256 + threadIdx.x;
  if (mat == 0) {
    if (idx < 528 * 192) {
      int nn = idx / 192, k = idx % 192;
      float v = 0.f;
      if (k < 176) {
        int sel = nn / 176, c = nn % 176;
        const float* W = tp ? (sel == 0 ? tWq : sel == 1 ? tWk : tWv)
                            : (sel == 0 ? sWq : sel == 1 ? sWk : sWv);
        v = W[(long)li * 176 * 176 + k * 176 + c];
      }
      dst[idx] = f2b(v);
    }
    if (idx < 528) {
      int sel = idx / 176, c = idx % 176;
      const float* bb = tp ? (sel == 0 ? tbq : sel == 1 ? tbk : tbv)
                           : (sel == 0 ? sbq : sel == 1 ? sbk : sbv);
      bqkv[layer * 528 + idx] = bb[li * 176 + c];
    }
  } else if (mat == 1) {
    if (idx < 176 * 192) {
      int nn = idx / 192, k = idx % 192;     // k' = 48h + dd
      int hh = k / 48, dd = k % 48;
      float v = (dd < 44)
          ? (tp ? tWo : sWo)[(long)li * 176 * 176 + (hh * 44 + dd) * 176 + nn]
          : 0.f;
      dst[101376 + idx] = f2b(v);
    }
  } else if (mat == 2) {
    if (idx < 256 * 192) {
      int nn = idx / 192, k = idx % 192;
      float v = (k < 176) ? (tp ? tW1 : sW1)[(long)li * 176 * 256 + k * 256 + nn] : 0.f;
      dst[135168 + idx] = f2b(v);
    }
  } else {
    if (idx < 176 * 256) {
      int nn = idx / 256, k = idx % 256;
      float v = (tp ? tW2 : sW2)[(long)li * 256 * 176 + k * 176 + nn];
      dst[184320 + idx] = f2b(v);
    }
  }
}

// ---------------- embedding (chunk of Mc tokens starting at tok0) ----------------
__global__ __launch_bounds__(256) void embed_kernel(
    const float* __restrict__ x, const float* __restrict__ W_in,
    const float* __restrict__ b_in, const float* __restrict__ tod,
    const float* __restrict__ dow, const float* __restrict__ node,
    const float* __restrict__ adp, float* __restrict__ h,
    unsigned short* __restrict__ hb, long tok0, long Mc) {
  long i = (long)blockIdx.x * 256 + threadIdx.x;  // over Mc*192
  if (i >= Mc * KP) return;
  int dp = (int)(i % KP);
  long tok = i / KP;           // chunk-local
  if (dp >= DM) { hb[tok * KP + dp] = 0; return; }
  long tg = tok0 + tok;        // global token
  int n = (int)(tg % NN);
  long bt = tg / NN;
  int t = (int)(bt % TT);
  float v;
  int d = dp;
  if (d < 24) {
    const float* xp = x + tg * 3;
    v = xp[0] * W_in[d] + xp[1] * W_in[24 + d] + xp[2] * W_in[48 + d] + b_in[d];
  } else if (d < 48) {
    float x1 = x[tg * 3 + 1];
    int idx = (int)(x1 * 288.0f);
    idx = idx < 0 ? 0 : (idx > 287 ? 287 : idx);
    v = tod[idx * 24 + (d - 24)];
  } else if (d < 72) {
    float x2 = x[tg * 3 + 2];
    int idx = (int)x2;
    idx = idx < 0 ? 0 : (idx > 6 ? 6 : idx);
    v = dow[idx * 24 + (d - 48)];
  } else if (d < 96) {
    v = node[n * 24 + (d - 72)];
  } else {
    v = adp[((long)t * NN + n) * 80 + (d - 96)];
  }
  h[tok * DM + d] = v;
  hb[tok * KP + d] = f2b(v);
}

// ---------------- generic MFMA GEMM: C[M,N] = A@Wt^T + bias ----------------
// QKVPAD: output to 12 head-major planes [plane][tok][48], pads zeroed.
template <int KSTEPS, bool RELU, bool OUTBF16, bool QKVPAD>
__global__ __launch_bounds__(256) void gemm_bias(
    const unsigned short* __restrict__ A, int lda,
    const unsigned short* __restrict__ Wt, const float* __restrict__ bias,
    void* __restrict__ out, int ldo, long M, int N, int tpy, long PS) {
  int wave = threadIdx.x >> 6;
  int lane = threadIdx.x & 63;
  long wrow = ((long)blockIdx.x * 4 + wave) * 64;
  if (wrow >= M) return;
  int lrow = lane & 15;
  int kq = lane >> 4;  // 0..3
  bfv8 a[4][KSTEPS];
#pragma unroll
  for (int rf = 0; rf < 4; ++rf) {
    long ar = wrow + rf * 16 + lrow;
    if (ar >= M) ar = M - 1;  // clamp tail reads
#pragma unroll
    for (int ks = 0; ks < KSTEPS; ++ks)
      a[rf][ks] = *(const bfv8*)(A + ar * (long)lda + kq * 8 + ks * 32);
  }
  int ntiles = N >> 4;
  int nt0 = blockIdx.y * tpy;
  int ntE = nt0 + tpy;
  if (ntE > ntiles) ntE = ntiles;
  for (int nt = nt0; nt < ntE; ++nt) {
    int col = nt * 16 + lrow;
    const unsigned short* bp = Wt + (long)col * lda + kq * 8;
    f32x4 acc[4] = {{0, 0, 0, 0}, {0, 0, 0, 0}, {0, 0, 0, 0}, {0, 0, 0, 0}};
#pragma unroll
    for (int ks = 0; ks < KSTEPS; ++ks) {
      bfv8 b = *(const bfv8*)(bp + ks * 32);
#pragma unroll
      for (int rf = 0; rf < 4; ++rf)
        acc[rf] = __builtin_amdgcn_mfma_f32_16x16x32_bf16(a[rf][ks], b, acc[rf], 0, 0, 0);
    }
    float bv = bias[col];
    long obase = 0;
    int ocol = col;
    if (QKVPAD) {
      int sel = col / 176, rem = col - sel * 176;
      int hh = rem / 44, dd = rem - hh * 44;
      obase = (long)(sel * 4 + hh) * PS;
      ocol = dd;
    }
#pragma unroll
    for (int rf = 0; rf < 4; ++rf) {
      long r0 = wrow + rf * 16 + kq * 4;
#pragma unroll
      for (int r = 0; r < 4; ++r) {
        if (r0 + r >= M) continue;  // guard tail stores
        float v = acc[rf][r] + bv;
        if (RELU) v = fmaxf(v, 0.f);
        long idx = QKVPAD ? (obase + (r0 + r) * 48 + ocol)
                          : ((r0 + r) * (long)ldo + ocol);
        if (OUTBF16)
          ((unsigned short*)out)[idx] = f2b(v);
        else
          ((float*)out)[idx] = v;
      }
    }
  }
  if (QKVPAD && blockIdx.y == 0) {
    long row = wrow + lane;
    if (row < M) {
#pragma unroll
      for (int p = 0; p < 12; ++p)
        *(ull*)((unsigned short*)out + (long)p * PS + row * 48 + 44) = 0ULL;
    }
  }
}

// ------- fused GEMM (N=176) + bias + residual + LayerNorm -> h, hb -----------
// One block = 64 rows; 4 waves split the 11 N-tiles (wave w: nt = w, w+4, w+8).
// AHM: A from 4 head planes (k' = 48h + d).
template <int KSTEPS, bool AHM>
__global__ __launch_bounds__(256) void gemm_ln_fused(
    const unsigned short* __restrict__ A, int lda,
    const unsigned short* __restrict__ Wt, const float* __restrict__ bias,
    const float* __restrict__ g, const float* __restrict__ beta,
    float* __restrict__ h, unsigned short* __restrict__ hb,
    long M, long PS) {
  __shared__ float2 part[64][5];  // [row][wave 0..3, 4 = final {mean,rstd}]
  int w = threadIdx.x >> 6;
  int lane = threadIdx.x & 63;
  long wrow = (long)blockIdx.x * 64;
  if (wrow >= M) return;  // uniform over block
  int lrow = lane & 15;
  int kq = lane >> 4;
  bfv8 a[4][KSTEPS];
#pragma unroll
  for (int rf = 0; rf < 4; ++rf) {
    long ar = wrow + rf * 16 + lrow;
    if (ar >= M) ar = M - 1;
#pragma unroll
    for (int ks = 0; ks < KSTEPS; ++ks) {
      if (AHM) {
        int kp0 = ks * 32 + kq * 8;
        int hh = kp0 / 48;
        int off = kp0 - hh * 48;
        a[rf][ks] = *(const bfv8*)(A + (long)hh * PS + ar * 48 + off);
      } else {
        a[rf][ks] = *(const bfv8*)(A + ar * (long)lda + kq * 8 + ks * 32);
      }
    }
  }
  f32x4 acc[3][4];
#pragma unroll
  for (int i = 0; i < 3; ++i) {
    int nt = w + 4 * i;
    if (nt >= 11) continue;
    int col = nt * 16 + lrow;
    const unsigned short* bp = Wt + (long)col * lda + kq * 8;
    f32x4 c0 = {0, 0, 0, 0}, c1 = {0, 0, 0, 0}, c2 = {0, 0, 0, 0}, c3 = {0, 0, 0, 0};
#pragma unroll
    for (int ks = 0; ks < KSTEPS; ++ks) {
      bfv8 b = *(const bfv8*)(bp + ks * 32);
      c0 = __builtin_amdgcn_mfma_f32_16x16x32_bf16(a[0][ks], b, c0, 0, 0, 0);
      c1 = __builtin_amdgcn_mfma_f32_16x16x32_bf16(a[1][ks], b, c1, 0, 0, 0);
      c2 = __builtin_amdgcn_mfma_f32_16x16x32_bf16(a[2][ks], b, c2, 0, 0, 0);
      c3 = __builtin_amdgcn_mfma_f32_16x16x32_bf16(a[3][ks], b, c3, 0, 0, 0);
    }
    acc[i][0] = c0; acc[i][1] = c1; acc[i][2] = c2; acc[i][3] = c3;
  }
  float sum[16], ss[16];
#pragma unroll
  for (int j = 0; j < 16; ++j) { sum[j] = 0.f; ss[j] = 0.f; }
#pragma unroll
  for (int i = 0; i < 3; ++i) {
    int nt = w + 4 * i;
    if (nt >= 11) continue;
    int col = nt * 16 + lrow;
    float bv = bias[col];
#pragma unroll
    for (int rf = 0; rf < 4; ++rf)
#pragma unroll
      for (int r = 0; r < 4; ++r) {
        long row = wrow + rf * 16 + kq * 4 + r;
        long rr = row < M ? row : M - 1;
        float v = acc[i][rf][r] + bv + h[rr * DM + col];
        acc[i][rf][r] = v;
        sum[rf * 4 + r] += v;
        ss[rf * 4 + r] += v * v;
      }
  }
#pragma unroll
  for (int j = 0; j < 16; ++j) {
#pragma unroll
    for (int o = 1; o < 16; o <<= 1) {
      sum[j] += __shfl_xor(sum[j], o);
      ss[j] += __shfl_xor(ss[j], o);
    }
  }
  if (lrow == 0) {
#pragma unroll
    for (int rf = 0; rf < 4; ++rf)
#pragma unroll
      for (int r = 0; r < 4; ++r)
        part[rf * 16 + kq * 4 + r][w] = float2{sum[rf * 4 + r], ss[rf * 4 + r]};
  }
  __syncthreads();
  if (w == 0) {
    float s = 0.f, q = 0.f;
#pragma unroll
    for (int ww = 0; ww < 4; ++ww) {
      float2 p = part[lane][ww];
      s += p.x; q += p.y;
    }
    float mean = s * (1.f / 176.f);
    float var = q * (1.f / 176.f) - mean * mean;
    part[lane][4] = float2{mean, rsqrtf(var + 1e-5f)};
  }
  __syncthreads();
#pragma unroll
  for (int i = 0; i < 3; ++i) {
    int nt = w + 4 * i;
    if (nt >= 11) continue;
    int col = nt * 16 + lrow;
    float gv = g[col], bv2 = beta[col];
#pragma unroll
    for (int rf = 0; rf < 4; ++rf)
#pragma unroll
      for (int r = 0; r < 4; ++r) {
        int lr = rf * 16 + kq * 4 + r;
        long row = wrow + lr;
        if (row >= M) continue;
        float2 st = part[lr][4];
        float y = (acc[i][rf][r] - st.x) * st.y * gv + bv2;
        h[row * DM + col] = y;
        hb[row * KP + col] = f2b(y);
      }
  }
  if (w == 0) {
    long row = wrow + lane;
    if (row < M) {
      ull* zp = (ull*)(hb + row * KP + DM);
      zp[0] = 0ULL; zp[1] = 0ULL; zp[2] = 0ULL; zp[3] = 0ULL;
    }
  }
}

// ------- fully fused FFN: relu(hb@W1+b1)@W2+b2 + residual + LN -> h, hb -------
__global__ __launch_bounds__(256) void ffn_fused(
    const unsigned short* __restrict__ A,   // hb [M][KP]
    const unsigned short* __restrict__ W1t, const float* __restrict__ b1,
    const unsigned short* __restrict__ W2t, const float* __restrict__ b2,
    const float* __restrict__ g, const float* __restrict__ beta,
    float* __restrict__ h, unsigned short* __restrict__ hb, long M) {
  __shared__ unsigned short mid[64 * MLS];  // 33792 B
  __shared__ float2 part[64][5];
  int w = threadIdx.x >> 6;
  int lane = threadIdx.x & 63;
  long wrow = (long)blockIdx.x * 64;
  if (wrow >= M) return;  // uniform over block
  int lrow = lane & 15;
  int kq = lane >> 4;
  // ---- GEMM1 ----
  {
    bfv8 a1[4][6];
#pragma unroll
    for (int rf = 0; rf < 4; ++rf) {
      long ar = wrow + rf * 16 + lrow;
      if (ar >= M) ar = M - 1;
#pragma unroll
      for (int ks = 0; ks < 6; ++ks)
        a1[rf][ks] = *(const bfv8*)(A + ar * (long)KP + kq * 8 + ks * 32);
    }
#pragma unroll
    for (int i = 0; i < 4; ++i) {
      int nt = w * 4 + i;
      int col = nt * 16 + lrow;
      const unsigned short* bp = W1t + (long)col * KP + kq * 8;
      f32x4 c0 = {0, 0, 0, 0}, c1 = {0, 0, 0, 0}, c2 = {0, 0, 0, 0}, c3 = {0, 0, 0, 0};
#pragma unroll
      for (int ks = 0; ks < 6; ++ks) {
        bfv8 b = *(const bfv8*)(bp + ks * 32);
        c0 = __builtin_amdgcn_mfma_f32_16x16x32_bf16(a1[0][ks], b, c0, 0, 0, 0);
        c1 = __builtin_amdgcn_mfma_f32_16x16x32_bf16(a1[1][ks], b, c1, 0, 0, 0);
        c2 = __builtin_amdgcn_mfma_f32_16x16x32_bf16(a1[2][ks], b, c2, 0, 0, 0);
        c3 = __builtin_amdgcn_mfma_f32_16x16x32_bf16(a1[3][ks], b, c3, 0, 0, 0);
      }
      float bv = b1[col];
      f32x4 cc[4] = {c0, c1, c2, c3};
#pragma unroll
      for (int rf = 0; rf < 4; ++rf)
#pragma unroll
        for (int r = 0; r < 4; ++r) {
          float v = fmaxf(cc[rf][r] + bv, 0.f);
          mid[(rf * 16 + kq * 4 + r) * MLS + col] = f2b(v);
        }
    }
  }
  __syncthreads();
  // ---- GEMM2 + LN (A from LDS, K=256 in 2 halves) ----
  f32x4 acc[3][4];
#pragma unroll
  for (int i = 0; i < 3; ++i)
#pragma unroll
    for (int rf = 0; rf < 4; ++rf) acc[i][rf] = f32x4{0.f, 0.f, 0.f, 0.f};
#pragma unroll
  for (int half = 0; half < 2; ++half) {
    bfv8 a2[4][4];
#pragma unroll
    for (int rf = 0; rf < 4; ++rf)
#pragma unroll
      for (int ks = 0; ks < 4; ++ks)
        a2[rf][ks] = *(const bfv8*)(&mid[(rf * 16 + lrow) * MLS + kq * 8 + (half * 4 + ks) * 32]);
#pragma unroll
    for (int i = 0; i < 3; ++i) {
      int nt = w + 4 * i;
      if (nt >= 11) continue;
      int col = nt * 16 + lrow;
      const unsigned short* bp = W2t + (long)col * FFD + kq * 8 + half * 128;
      f32x4 c0 = acc[i][0], c1 = acc[i][1], c2 = acc[i][2], c3 = acc[i][3];
#pragma unroll
      for (int ks = 0; ks < 4; ++ks) {
        bfv8 b = *(const bfv8*)(bp + ks * 32);
        c0 = __builtin_amdgcn_mfma_f32_16x16x32_bf16(a2[0][ks], b, c0, 0, 0, 0);
        c1 = __builtin_amdgcn_mfma_f32_16x16x32_bf16(a2[1][ks], b, c1, 0, 0, 0);
        c2 = __builtin_amdgcn_mfma_f32_16x16x32_bf16(a2[2][ks], b, c2, 0, 0, 0);
        c3 = __builtin_amdgcn_mfma_f32_16x16x32_bf16(a2[3][ks], b, c3, 0, 0, 0);
      }
      acc[i][0] = c0; acc[i][1] = c1; acc[i][2] = c2; acc[i][3] = c3;
    }
  }
  float sum[16], ss[16];
#pragma unroll
  for (int j = 0; j < 16; ++j) { sum[j] = 0.f; ss[j] = 0.f; }
#pragma unroll
  for (int i = 0; i < 3; ++i) {
    int nt = w + 4 * i;
    if (nt >= 11) continue;
    int col = nt * 16 + lrow;
    float bv = b2[col];
#pragma unroll
    for (int rf = 0; rf < 4; ++rf)
#pragma unroll
      for (int r = 0; r < 4; ++r) {
        long row = wrow + rf * 16 + kq * 4 + r;
        long rr = row < M ? row : M - 1;
        float v = acc[i][rf][r] + bv + h[rr * DM + col];
        acc[i][rf][r] = v;
        sum[rf * 4 + r] += v;
        ss[rf * 4 + r] += v * v;
      }
  }
#pragma unroll
  for (int j = 0; j < 16; ++j) {
#pragma unroll
    for (int o = 1; o < 16; o <<= 1) {
      sum[j] += __shfl_xor(sum[j], o);
      ss[j] += __shfl_xor(ss[j], o);
    }
  }
  if (lrow == 0) {
#pragma unroll
    for (int rf = 0; rf < 4; ++rf)
#pragma unroll
      for (int r = 0; r < 4; ++r)
        part[rf * 16 + kq * 4 + r][w] = float2{sum[rf * 4 + r], ss[rf * 4 + r]};
  }
  __syncthreads();
  if (w == 0) {
    float s = 0.f, q = 0.f;
#pragma unroll
    for (int ww = 0; ww < 4; ++ww) {
      float2 p = part[lane][ww];
      s += p.x; q += p.y;
    }
    float mean = s * (1.f / 176.f);
    float var = q * (1.f / 176.f) - mean * mean;
    part[lane][4] = float2{mean, rsqrtf(var + 1e-5f)};
  }
  __syncthreads();
#pragma unroll
  for (int i = 0; i < 3; ++i) {
    int nt = w + 4 * i;
    if (nt >= 11) continue;
    int col = nt * 16 + lrow;
    float gv = g[col], bv2 = beta[col];
#pragma unroll
    for (int rf = 0; rf < 4; ++rf)
#pragma unroll
      for (int r = 0; r < 4; ++r) {
        int lr = rf * 16 + kq * 4 + r;
        long row = wrow + lr;
        if (row >= M) continue;
        float2 st = part[lr][4];
        float y = (acc[i][rf][r] - st.x) * st.y * gv + bv2;
        h[row * DM + col] = y;
        hb[row * KP + col] = f2b(y);
      }
  }
  if (w == 0) {
    long row = wrow + lane;
    if (row < M) {
      ull* zp = (ull*)(hb + row * KP + DM);
      zp[0] = 0ULL; zp[1] = 0ULL; zp[2] = 0ULL; zp[3] = 0ULL;
    }
  }
}

// ---------------- temporal attention (L = 12), LDS-staged per (b, 4-node tile) --
__global__ __launch_bounds__(256) void attn_temporal_lds(
    const unsigned short* __restrict__ qkvh, unsigned short* __restrict__ atth,
    long PS) {
  __shared__ unsigned short ld[4 * 12 * TS];  // 56064 B
  int tile = blockIdx.x % NTILE;
  int b = blockIdx.x / NTILE;   // chunk-local
  int n0 = tile * 4;
  for (int idx = threadIdx.x; idx < 3456; idx += 256) {
    int p = idx / 288;
    int rem = idx % 288;
    int t = rem / 24;
    int rem2 = rem % 24;
    int j = rem2 / 6, e = rem2 % 6;
    uiv4 v = {0, 0, 0, 0};
    int n = n0 + j;
    if (n < NN)
      v = *(const uiv4*)(qkvh + (long)p * PS + ((long)(b * TT + t) * NN + n) * 48 + e * 8);
    *(uiv4*)(&ld[(j * 12 + p) * TS + t * 48 + e * 8]) = v;
  }
  __syncthreads();
  int tid = threadIdx.x;
  if (tid >= 192) return;
  int j = tid / 48, hl = tid % 48;
  int hh = hl / 12, l = hl % 12;
  int n = n0 + j;
  if (n >= NN) return;
  const float scale = 0.15075567228888181f;  // 1/sqrt(44)
  float q[HD];
  const unsigned short* qp = &ld[(j * 12 + hh) * TS + l * 48];
#pragma unroll
  for (int d = 0; d < HD; ++d) q[d] = b2f(qp[d]) * scale;
  float s[TT];
  float mx = -1e30f;
#pragma unroll
  for (int m = 0; m < TT; ++m) {
    const unsigned short* kp = &ld[(j * 12 + 4 + hh) * TS + m * 48];
    float acc = 0.f;
#pragma unroll
    for (int d = 0; d < HD; ++d) acc += q[d] * b2f(kp[d]);
    s[m] = acc;
    mx = fmaxf(mx, acc);
  }
  float den = 0.f;
#pragma unroll
  for (int m = 0; m < TT; ++m) { s[m] = __expf(s[m] - mx); den += s[m]; }
  float inv = 1.f / den;
  float o[HD];
#pragma unroll
  for (int d = 0; d < HD; ++d) o[d] = 0.f;
#pragma unroll
  for (int m = 0; m < TT; ++m) {
    const unsigned short* vp = &ld[(j * 12 + 8 + hh) * TS + m * 48];
    float p = s[m] * inv;
#pragma unroll
    for (int d = 0; d < HD; ++d) o[d] += p * b2f(vp[d]);
  }
  unsigned short* op = atth + (long)hh * PS + ((long)(b * TT + l) * NN + n) * 48;
#pragma unroll
  for (int d = 0; d < HD; d += 2) {
    unsigned u = (unsigned)f2b(o[d]) | ((unsigned)f2b(o[d + 1]) << 16);
    *(unsigned*)(op + d) = u;
  }
  *(ull*)(op + 44) = 0ULL;  // pad
}

// ---------------- spatial attention (L = 307) via MFMA, online softmax ----------
// 256 threads / 4 waves per block (finer scheduling granularity; LDS 32 KB ->
// 4 blocks/CU at 124 VGPR). Defer-max (T13). K read directly from global
// (L1/L2-resident); Q/K high k-half (k>=48) zeroed in registers for kq>=2.
#define VTS 332  // Vt row stride (elems)
__global__ __launch_bounds__(256, 4) void attn_spatial_mfma(
    const unsigned short* __restrict__ qkvh, unsigned short* __restrict__ atth,
    long PS) {
  __shared__ unsigned short Vt[48 * VTS];   // 31872 B
  int h = blockIdx.x & 3;
  int bt = blockIdx.x >> 2;
  long tokbase = (long)bt * NN;
  const unsigned short* qbase = qkvh + (long)h * PS + tokbase * 48;
  const unsigned short* kbase = qkvh + (long)(4 + h) * PS + tokbase * 48;
  const unsigned short* vbase = qkvh + (long)(8 + h) * PS + tokbase * 48;
  int tid = threadIdx.x;

  // stage V transposed via 16B loads: Vt[d][m], d=0..47 (44..47 zero from pad)
  for (int task = tid; task < 480; task += 256) {
    int m0 = (task / 6) * 4, c = task % 6;
    const unsigned short* vb = vbase + c * 8;
    uiv4 r0 = {0, 0, 0, 0}, r1 = {0, 0, 0, 0}, r2 = {0, 0, 0, 0}, r3 = {0, 0, 0, 0};
    if (m0 + 0 < NN) r0 = *(const uiv4*)(vb + (long)(m0 + 0) * 48);
    if (m0 + 1 < NN) r1 = *(const uiv4*)(vb + (long)(m0 + 1) * 48);
    if (m0 + 2 < NN) r2 = *(const uiv4*)(vb + (long)(m0 + 2) * 48);
    if (m0 + 3 < NN) r3 = *(const uiv4*)(vb + (long)(m0 + 3) * 48);
#pragma unroll
    for (int j = 0; j < 8; ++j) {
      int w32 = j >> 1, sh = (j & 1) * 16;
      ull o = (ull)((r0[w32] >> sh) & 0xFFFFu) |
              ((ull)((r1[w32] >> sh) & 0xFFFFu) << 16) |
              ((ull)((r2[w32] >> sh) & 0xFFFFu) << 32) |
              ((ull)((r3[w32] >> sh) & 0xFFFFu) << 48);
      *(ull*)(&Vt[(c * 8 + j) * VTS + m0]) = o;
    }
  }
  __syncthreads();

  int w = tid >> 6;          // 0..3
  int lane = tid & 63;
  int lrow = lane & 15;
  int kq = lane >> 4;
  bool hiK = (kq >= 2);      // k in [48,64): both operands zero
  const float kscale = 0.2174944602f;  // 1/sqrt(44)*log2(e)

  bfv8 bz;
#pragma unroll
  for (int j = 0; j < 8; ++j) bz[j] = (__bf16)0.f;

#pragma unroll
  for (int qi = 0; qi < 5; ++qi) {
    int qt = qi * 4 + w;     // 4 waves x 5 tiles = 20
    int ql = qt * 16 + lrow;
    int qc = ql < NN ? ql : NN - 1;
    const unsigned short* qrow = qbase + (long)qc * 48;
    bfv8 qb8a = *(const bfv8*)(qrow + kq * 8);
    bfv8 qb8b = hiK ? bz : *(const bfv8*)(qrow + 32 + kq * 8);

    float m_run = -1e30f, den = 0.f;
    f32x4 o0 = {0.f, 0.f, 0.f, 0.f}, o1 = {0.f, 0.f, 0.f, 0.f}, o2 = {0.f, 0.f, 0.f, 0.f};
#pragma unroll
    for (int ct = 0; ct < 20; ++ct) {
      const unsigned short* kp = kbase + (long)(ct * 16 + lrow) * 48;
      bfv8 k8a = *(const bfv8*)(kp + kq * 8);
      bfv8 k8b = hiK ? bz : *(const bfv8*)(kp + 32 + kq * 8);
      f32x4 s = {0.f, 0.f, 0.f, 0.f};
      s = __builtin_amdgcn_mfma_f32_16x16x32_bf16(k8a, qb8a, s, 0, 0, 0);
      s = __builtin_amdgcn_mfma_f32_16x16x32_bf16(k8b, qb8b, s, 0, 0, 0);
#pragma unroll
      for (int r = 0; r < 4; ++r) {
        float v = s[r] * kscale;
        if (ct == 19 && (kq * 4 + r) >= 3) v = -1e30f;  // m >= 307 (masks OOR rows)
        s[r] = v;
      }
      float smax = fmaxf(fmaxf(s[0], s[1]), fmaxf(s[2], s[3]));
      if (!__all(smax <= m_run + 8.f)) {
        smax = fmaxf(smax, __shfl_xor(smax, 16));
        smax = fmaxf(smax, __shfl_xor(smax, 32));
        float m_new = fmaxf(m_run, smax);
        float corr = exp2f(m_run - m_new);
        m_run = m_new;
        den *= corr;
        o0 = o0 * corr;
        o1 = o1 * corr;
        o2 = o2 * corr;
      }
      float p0 = exp2f(s[0] - m_run);
      float p1 = exp2f(s[1] - m_run);
      float p2 = exp2f(s[2] - m_run);
      float p3 = exp2f(s[3] - m_run);
      den += (p0 + p1) + (p2 + p3);
      sv4 pb = {(short)f2b(p0), (short)f2b(p1), (short)f2b(p2), (short)f2b(p3)};
      int mb = ct * 16 + kq * 4;
      sv4 a0 = *(const sv4*)(&Vt[(0 * 16 + lrow) * VTS + mb]);
      sv4 a1 = *(const sv4*)(&Vt[(1 * 16 + lrow) * VTS + mb]);
      sv4 a2 = *(const sv4*)(&Vt[(2 * 16 + lrow) * VTS + mb]);
      o0 = mfma16x16x16bf(a0, pb, o0);
      o1 = mfma16x16x16bf(a1, pb, o1);
      o2 = mfma16x16x16bf(a2, pb, o2);
    }
    den += __shfl_xor(den, 16);
    den += __shfl_xor(den, 32);
    float inv = 1.f / den;

    if (ql < NN) {
      unsigned short* dst = atth + (long)h * PS + (tokbase + ql) * 48;
      int db = kq * 4;
      {
        ull u = (ull)f2b(o0[0] * inv) | ((ull)f2b(o0[1] * inv) << 16) |
                ((ull)f2b(o0[2] * inv) << 32) | ((ull)f2b(o0[3] * inv) << 48);
        *(ull*)(dst + db) = u;
      }
      {
        ull u = (ull)f2b(o1[0] * inv) | ((ull)f2b(o1[1] * inv) << 16) |
                ((ull)f2b(o1[2] * inv) << 32) | ((ull)f2b(o1[3] * inv) << 48);
        *(ull*)(dst + 16 + db) = u;
      }
      if (db < 12) {
        ull u = (ull)f2b(o2[0] * inv) | ((ull)f2b(o2[1] * inv) << 16) |
                ((ull)f2b(o2[2] * inv) << 32) | ((ull)f2b(o2[3] * inv) << 48);
        *(ull*)(dst + 32 + db) = u;
      } else {
        *(ull*)(dst + 44) = 0ULL;
      }
    }
  }
}

// ---------------- output projection (chunk of nb batches starting at b0) ----------
__global__ __launch_bounds__(64) void out_kernel(
    const float* __restrict__ h, const float* __restrict__ Wout,
    const float* __restrict__ bout, float* __restrict__ out, int b0) {
  int bn = blockIdx.x;  // chunk-local b*307+n
  int n = bn % NN, bl = bn / NN;
  int b = b0 + bl;
  int lane = threadIdx.x;
  float acc[TT];
#pragma unroll
  for (int j = 0; j < TT; ++j) acc[j] = 0.f;
  for (int k = lane; k < TT * DM; k += 64) {
    int t = k / DM, d = k % DM;
    float a = h[((long)(bl * TT + t) * NN + n) * DM + d];
    const float* wp = Wout + (long)k * TT;
#pragma unroll
    for (int j = 0; j < TT; ++j) acc[j] += a * wp[j];
  }
#pragma unroll
  for (int j = 0; j < TT; ++j)
    for (int o = 32; o > 0; o >>= 1) acc[j] += __shfl_xor(acc[j], o);
  if (lane < TT) out[((long)b * TT + lane) * NN + n] = acc[lane] + bout[lane];
}

// ---------------- launch ----------------
// Input order = setup_inputs() dict insertion order:
//  0 x, 1 W_in, 2 b_in, 3 tod_emb, 4 dow_emb, 5 node_emb, 6 adp_emb,
//  7 Wout, 8 bout,
//  9 tWq..24 tB2 (temporal block), 25 sWq..40 sB2 (spatial block)
extern "C" void kernel_launch(void* const* d_in, const int* in_sizes, int n_in,
                              void* d_out, int out_size, void* d_ws, size_t ws_size,
                              hipStream_t stream) {
  char* ws = (char*)d_ws;
  unsigned short* wbase = (unsigned short*)ws;           // 2,752,512 B
  float* bqkv = (float*)(ws + 2752512L);                 //    12,672 B
  char* dyn = ws + 2765184L;

  // per-token bytes: h(704) + hb(384) + qkvh(1152) + atth(384)
  const long per_tok = 2624;
  int nb = 0;
  for (int c = 32; c >= 1; --c) {
    if (2765184L + (long)c * TPB * per_tok <= (long)ws_size) { nb = c; break; }
  }
  if (nb == 0) return;

  const long Mal = (long)nb * TPB;
  const long PS = Mal * 48;  // plane stride (elems)
  float* h = (float*)dyn;
  unsigned short* hb = (unsigned short*)(dyn + Mal * 704);
  unsigned short* qkvh = (unsigned short*)(dyn + Mal * 1088);
  unsigned short* atth = (unsigned short*)(dyn + Mal * 2240);

#define DF(i) ((const float*)d_in[i])

  prep_weights<<<dim3(396, 6, 4), 256, 0, stream>>>(
      DF(9), DF(11), DF(13), DF(15), DF(17), DF(19),
      DF(25), DF(27), DF(29), DF(31), DF(33), DF(35),
      DF(10), DF(12), DF(14), DF(26), DF(28), DF(30), wbase, bqkv);

  for (int b0 = 0; b0 < BB; b0 += nb) {
    int nb_cur = (BB - b0 < nb) ? (BB - b0) : nb;
    const long Mc = (long)nb_cur * TPB;
    int gx = (int)((Mc + 255) / 256);
    int gx64 = (int)((Mc + 63) / 64);

    embed_kernel<<<(int)((Mc * KP + 255) / 256), 256, 0, stream>>>(
        DF(0), DF(1), DF(2), DF(3), DF(4), DF(5), DF(6), h, hb,
        (long)b0 * TPB, Mc);

    for (int l = 0; l < 6; ++l) {
      int base = (l < 3) ? 9 : 25;
      int li = l % 3;
      const unsigned short* wl = wbase + (long)l * 229376;
      const unsigned short* Wqkv = wl;
      const unsigned short* Wo = wl + 101376;
      const unsigned short* W1 = wl + 135168;
      const unsigned short* W2 = wl + 184320;
      const float* bo = DF(base + 7) + li * 176;
      const float* b1 = DF(base + 9) + li * 256;
      const float* b2 = DF(base + 11) + li * 176;
      const float* g1 = DF(base + 12) + li * 176;
      const float* B1 = DF(base + 13) + li * 176;
      const float* g2 = DF(base + 14) + li * 176;
      const float* B2 = DF(base + 15) + li * 176;

      gemm_bias<6, false, true, true><<<dim3(gx, 3), 256, 0, stream>>>(
          hb, KP, Wqkv, bqkv + l * 528, qkvh, 0, Mc, 528, 11, PS);

      if (l < 3) {
        attn_temporal_lds<<<nb_cur * NTILE, 256, 0, stream>>>(qkvh, atth, PS);
      } else {
        attn_spatial_mfma<<<nb_cur * TT * NH, 256, 0, stream>>>(qkvh, atth, PS);
      }

      gemm_ln_fused<6, true><<<gx64, 256, 0, stream>>>(
          atth, KP, Wo, bo, g1, B1, h, hb, Mc, PS);

      ffn_fused<<<gx64, 256, 0, stream>>>(
          hb, W1, b1, W2, b2, g2, B2, h, hb, Mc);
    }

    out_kernel<<<nb_cur * NN, 64, 0, stream>>>(h, DF(7), DF(8), (float*)d_out, b0);
  }
#undef DF
}

// Round 21
// 2967.091 us; speedup vs baseline: 1.2939x; 1.2939x over previous
//
#include <hip/hip_runtime.h>

// ---------------- constants ----------------
#define BB 32
#define TPB 3684L        // tokens per batch element = T*N = 12*307
#define TT 12
#define NN 307
#define DM 176           // model dim
#define KP 192           // padded K for MFMA (176 -> 192)
#define FFD 256
#define NH 4
#define HD 44
#define NTILE 77         // ceil(307/4) node tiles for temporal attn
#define TS 584           // temporal LDS per-(node,plane) stride (12*48 + 8 pad)
#define MLS 264          // ffn mid LDS row stride (elems): 16B-aligned rows, dw%32=4

typedef __bf16 bfv8 __attribute__((ext_vector_type(8)));
typedef float f32x4 __attribute__((ext_vector_type(4)));
typedef short sv4 __attribute__((ext_vector_type(4)));
typedef unsigned int uiv4 __attribute__((ext_vector_type(4)));
typedef unsigned long long ull;

__device__ __forceinline__ float b2f(unsigned short h) {
  return __uint_as_float(((unsigned)h) << 16);
}
__device__ __forceinline__ unsigned short f2b(float f) {
  unsigned u = __float_as_uint(f);
  return (unsigned short)((u + 0x7FFFu + ((u >> 16) & 1u)) >> 16);  // RNE
}

// MFMA 16x16x16 bf16 wrapper (builtin if present; asm fallback with hazard nops)
__device__ __forceinline__ f32x4 mfma16x16x16bf(sv4 a, sv4 b, f32x4 c) {
#if __has_builtin(__builtin_amdgcn_mfma_f32_16x16x16bf16_1k)
  return __builtin_amdgcn_mfma_f32_16x16x16bf16_1k(a, b, c, 0, 0, 0);
#else
  f32x4 d = c;
  asm("v_mfma_f32_16x16x16_bf16 %0, %1, %2, %0\n\ts_nop 7\n\ts_nop 7"
      : "+v"(d) : "v"(a), "v"(b));
  return d;
#endif
}

// ---------------- weight prep: transpose + bf16 + K-pad ----------------
//   Wqkv_t [528][192] @ 0        (101376)
//   Wo_t   [176][192] @ 101376   (33792)  rows permuted to k' = 48h + d (pad=0)
//   W1_t   [256][192] @ 135168   (49152)
//   W2_t   [176][256] @ 184320   (45056)
__global__ void prep_weights(
    const float* __restrict__ tWq, const float* __restrict__ tWk,
    const float* __restrict__ tWv, const float* __restrict__ tWo,
    const float* __restrict__ tW1, const float* __restrict__ tW2,
    const float* __restrict__ sWq, const float* __restrict__ sWk,
    const float* __restrict__ sWv, const float* __restrict__ sWo,
    const float* __restrict__ sW1, const float* __restrict__ sW2,
    const float* __restrict__ tbq, const float* __restrict__ tbk,
    const float* __restrict__ tbv,
    const float* __restrict__ sbq, const float* __restrict__ sbk,
    const float* __restrict__ sbv,
    unsigned short* __restrict__ wbase, float* __restrict__ bqkv) {
  int layer = blockIdx.y;       // 0..5
  int mat = blockIdx.z;         // 0..3
  int li = layer % 3;
  bool tp = (layer < 3);
  unsigned short* dst = wbase + (long)layer * 229376;
  long idx = (long)blockIdx.x * 256 + threadIdx.x;
  if (mat == 0) {
    if (idx < 528 * 192) {
      int nn = idx / 192, k = idx % 192;
      float v = 0.f;
      if (k < 176) {
        int sel = nn / 176, c = nn % 176;
        const float* W = tp ? (sel == 0 ? tWq : sel == 1 ? tWk : tWv)
                            : (sel == 0 ? sWq : sel == 1 ? sWk : sWv);
        v = W[(long)li * 176 * 176 + k * 176 + c];
      }
      dst[idx] = f2b(v);
    }
    if (idx < 528) {
      int sel = idx / 176, c = idx % 176;
      const float* bb = tp ? (sel == 0 ? tbq : sel == 1 ? tbk : tbv)
                           : (sel == 0 ? sbq : sel == 1 ? sbk : sbv);
      bqkv[layer * 528 + idx] = bb[li * 176 + c];
    }
  } else if (mat == 1) {
    if (idx < 176 * 192) {
      int nn = idx / 192, k = idx % 192;     // k' = 48h + dd
      int hh = k / 48, dd = k % 48;
      float v = (dd < 44)
          ? (tp ? tWo : sWo)[(long)li * 176 * 176 + (hh * 44 + dd) * 176 + nn]
          : 0.f;
      dst[101376 + idx] = f2b(v);
    }
  } else if (mat == 2) {
    if (idx < 256 * 192) {
      int nn = idx / 192, k = idx % 192;
      float v = (k < 176) ? (tp ? tW1 : sW1)[(long)li * 176 * 256 + k * 256 + nn] : 0.f;
      dst[135168 + idx] = f2b(v);
    }
  } else {
    if (idx < 176 * 256) {
      int nn = idx / 256, k = idx % 256;
      float v = (tp ? tW2 : sW2)[(long)li * 256 * 176 + k * 176 + nn];
      dst[184320 + idx] = f2b(v);
    }
  }
}

// ---------------- embedding (chunk of Mc tokens starting at tok0) ----------------
__global__ __launch_bounds__(256) void embed_kernel(
    const float* __restrict__ x, const float* __restrict__ W_in,
    const float* __restrict__ b_in, const float* __restrict__ tod,
    const float* __restrict__ dow, const float* __restrict__ node,
    const float* __restrict__ adp, float* __restrict__ h,
    unsigned short* __restrict__ hb, long tok0, long Mc) {
  long i = (long)blockIdx.x * 256 + threadIdx.x;  // over Mc*192
  if (i >= Mc * KP) return;
  int dp = (int)(i % KP);
  long tok = i / KP;           // chunk-local
  if (dp >= DM) { hb[tok * KP + dp] = 0; return; }
  long tg = tok0 + tok;        // global token
  int n = (int)(tg % NN);
  long bt = tg / NN;
  int t = (int)(bt % TT);
  float v;
  int d = dp;
  if (d < 24) {
    const float* xp = x + tg * 3;
    v = xp[0] * W_in[d] + xp[1] * W_in[24 + d] + xp[2] * W_in[48 + d] + b_in[d];
  } else if (d < 48) {
    float x1 = x[tg * 3 + 1];
    int idx = (int)(x1 * 288.0f);
    idx = idx < 0 ? 0 : (idx > 287 ? 287 : idx);
    v = tod[idx * 24 + (d - 24)];
  } else if (d < 72) {
    float x2 = x[tg * 3 + 2];
    int idx = (int)x2;
    idx = idx < 0 ? 0 : (idx > 6 ? 6 : idx);
    v = dow[idx * 24 + (d - 48)];
  } else if (d < 96) {
    v = node[n * 24 + (d - 72)];
  } else {
    v = adp[((long)t * NN + n) * 80 + (d - 96)];
  }
  h[tok * DM + d] = v;
  hb[tok * KP + d] = f2b(v);
}

// ---------------- generic MFMA GEMM: C[M,N] = A@Wt^T + bias ----------------
// QKVPAD: output to 12 head-major planes [plane][tok][48], pads zeroed.
template <int KSTEPS, bool RELU, bool OUTBF16, bool QKVPAD>
__global__ __launch_bounds__(256) void gemm_bias(
    const unsigned short* __restrict__ A, int lda,
    const unsigned short* __restrict__ Wt, const float* __restrict__ bias,
    void* __restrict__ out, int ldo, long M, int N, int tpy, long PS) {
  int wave = threadIdx.x >> 6;
  int lane = threadIdx.x & 63;
  long wrow = ((long)blockIdx.x * 4 + wave) * 64;
  if (wrow >= M) return;
  int lrow = lane & 15;
  int kq = lane >> 4;  // 0..3
  bfv8 a[4][KSTEPS];
#pragma unroll
  for (int rf = 0; rf < 4; ++rf) {
    long ar = wrow + rf * 16 + lrow;
    if (ar >= M) ar = M - 1;  // clamp tail reads
#pragma unroll
    for (int ks = 0; ks < KSTEPS; ++ks)
      a[rf][ks] = *(const bfv8*)(A + ar * (long)lda + kq * 8 + ks * 32);
  }
  int ntiles = N >> 4;
  int nt0 = blockIdx.y * tpy;
  int ntE = nt0 + tpy;
  if (ntE > ntiles) ntE = ntiles;
  for (int nt = nt0; nt < ntE; ++nt) {
    int col = nt * 16 + lrow;
    const unsigned short* bp = Wt + (long)col * lda + kq * 8;
    f32x4 acc[4] = {{0, 0, 0, 0}, {0, 0, 0, 0}, {0, 0, 0, 0}, {0, 0, 0, 0}};
#pragma unroll
    for (int ks = 0; ks < KSTEPS; ++ks) {
      bfv8 b = *(const bfv8*)(bp + ks * 32);
#pragma unroll
      for (int rf = 0; rf < 4; ++rf)
        acc[rf] = __builtin_amdgcn_mfma_f32_16x16x32_bf16(a[rf][ks], b, acc[rf], 0, 0, 0);
    }
    float bv = bias[col];
    long obase = 0;
    int ocol = col;
    if (QKVPAD) {
      int sel = col / 176, rem = col - sel * 176;
      int hh = rem / 44, dd = rem - hh * 44;
      obase = (long)(sel * 4 + hh) * PS;
      ocol = dd;
    }
#pragma unroll
    for (int rf = 0; rf < 4; ++rf) {
      long r0 = wrow + rf * 16 + kq * 4;
#pragma unroll
      for (int r = 0; r < 4; ++r) {
        if (r0 + r >= M) continue;  // guard tail stores
        float v = acc[rf][r] + bv;
        if (RELU) v = fmaxf(v, 0.f);
        long idx = QKVPAD ? (obase + (r0 + r) * 48 + ocol)
                          : ((r0 + r) * (long)ldo + ocol);
        if (OUTBF16)
          ((unsigned short*)out)[idx] = f2b(v);
        else
          ((float*)out)[idx] = v;
      }
    }
  }
  if (QKVPAD && blockIdx.y == 0) {
    long row = wrow + lane;
    if (row < M) {
#pragma unroll
      for (int p = 0; p < 12; ++p)
        *(ull*)((unsigned short*)out + (long)p * PS + row * 48 + 44) = 0ULL;
    }
  }
}

// ------- fused GEMM (N=176) + bias + residual + LayerNorm -> h, hb -----------
// One block = 64 rows; 4 waves split the 11 N-tiles (wave w: nt = w, w+4, w+8).
// AHM: A from 4 head planes (k' = 48h + d).
template <int KSTEPS, bool AHM>
__global__ __launch_bounds__(256) void gemm_ln_fused(
    const unsigned short* __restrict__ A, int lda,
    const unsigned short* __restrict__ Wt, const float* __restrict__ bias,
    const float* __restrict__ g, const float* __restrict__ beta,
    float* __restrict__ h, unsigned short* __restrict__ hb,
    long M, long PS) {
  __shared__ float2 part[64][5];  // [row][wave 0..3, 4 = final {mean,rstd}]
  int w = threadIdx.x >> 6;
  int lane = threadIdx.x & 63;
  long wrow = (long)blockIdx.x * 64;
  if (wrow >= M) return;  // uniform over block
  int lrow = lane & 15;
  int kq = lane >> 4;
  bfv8 a[4][KSTEPS];
#pragma unroll
  for (int rf = 0; rf < 4; ++rf) {
    long ar = wrow + rf * 16 + lrow;
    if (ar >= M) ar = M - 1;
#pragma unroll
    for (int ks = 0; ks < KSTEPS; ++ks) {
      if (AHM) {
        int kp0 = ks * 32 + kq * 8;
        int hh = kp0 / 48;
        int off = kp0 - hh * 48;
        a[rf][ks] = *(const bfv8*)(A + (long)hh * PS + ar * 48 + off);
      } else {
        a[rf][ks] = *(const bfv8*)(A + ar * (long)lda + kq * 8 + ks * 32);
      }
    }
  }
  f32x4 acc[3][4];
#pragma unroll
  for (int i = 0; i < 3; ++i) {
    int nt = w + 4 * i;
    if (nt >= 11) continue;
    int col = nt * 16 + lrow;
    const unsigned short* bp = Wt + (long)col * lda + kq * 8;
    f32x4 c0 = {0, 0, 0, 0}, c1 = {0, 0, 0, 0}, c2 = {0, 0, 0, 0}, c3 = {0, 0, 0, 0};
#pragma unroll
    for (int ks = 0; ks < KSTEPS; ++ks) {
      bfv8 b = *(const bfv8*)(bp + ks * 32);
      c0 = __builtin_amdgcn_mfma_f32_16x16x32_bf16(a[0][ks], b, c0, 0, 0, 0);
      c1 = __builtin_amdgcn_mfma_f32_16x16x32_bf16(a[1][ks], b, c1, 0, 0, 0);
      c2 = __builtin_amdgcn_mfma_f32_16x16x32_bf16(a[2][ks], b, c2, 0, 0, 0);
      c3 = __builtin_amdgcn_mfma_f32_16x16x32_bf16(a[3][ks], b, c3, 0, 0, 0);
    }
    acc[i][0] = c0; acc[i][1] = c1; acc[i][2] = c2; acc[i][3] = c3;
  }
  float sum[16], ss[16];
#pragma unroll
  for (int j = 0; j < 16; ++j) { sum[j] = 0.f; ss[j] = 0.f; }
#pragma unroll
  for (int i = 0; i < 3; ++i) {
    int nt = w + 4 * i;
    if (nt >= 11) continue;
    int col = nt * 16 + lrow;
    float bv = bias[col];
#pragma unroll
    for (int rf = 0; rf < 4; ++rf)
#pragma unroll
      for (int r = 0; r < 4; ++r) {
        long row = wrow + rf * 16 + kq * 4 + r;
        long rr = row < M ? row : M - 1;
        float v = acc[i][rf][r] + bv + h[rr * DM + col];
        acc[i][rf][r] = v;
        sum[rf * 4 + r] += v;
        ss[rf * 4 + r] += v * v;
      }
  }
#pragma unroll
  for (int j = 0; j < 16; ++j) {
#pragma unroll
    for (int o = 1; o < 16; o <<= 1) {
      sum[j] += __shfl_xor(sum[j], o);
      ss[j] += __shfl_xor(ss[j], o);
    }
  }
  if (lrow == 0) {
#pragma unroll
    for (int rf = 0; rf < 4; ++rf)
#pragma unroll
      for (int r = 0; r < 4; ++r)
        part[rf * 16 + kq * 4 + r][w] = float2{sum[rf * 4 + r], ss[rf * 4 + r]};
  }
  __syncthreads();
  if (w == 0) {
    float s = 0.f, q = 0.f;
#pragma unroll
    for (int ww = 0; ww < 4; ++ww) {
      float2 p = part[lane][ww];
      s += p.x; q += p.y;
    }
    float mean = s * (1.f / 176.f);
    float var = q * (1.f / 176.f) - mean * mean;
    part[lane][4] = float2{mean, rsqrtf(var + 1e-5f)};
  }
  __syncthreads();
#pragma unroll
  for (int i = 0; i < 3; ++i) {
    int nt = w + 4 * i;
    if (nt >= 11) continue;
    int col = nt * 16 + lrow;
    float gv = g[col], bv2 = beta[col];
#pragma unroll
    for (int rf = 0; rf < 4; ++rf)
#pragma unroll
      for (int r = 0; r < 4; ++r) {
        int lr = rf * 16 + kq * 4 + r;
        long row = wrow + lr;
        if (row >= M) continue;
        float2 st = part[lr][4];
        float y = (acc[i][rf][r] - st.x) * st.y * gv + bv2;
        h[row * DM + col] = y;
        hb[row * KP + col] = f2b(y);
      }
  }
  if (w == 0) {
    long row = wrow + lane;
    if (row < M) {
      ull* zp = (ull*)(hb + row * KP + DM);
      zp[0] = 0ULL; zp[1] = 0ULL; zp[2] = 0ULL; zp[3] = 0ULL;
    }
  }
}

// ------- fully fused FFN: relu(hb@W1+b1)@W2+b2 + residual + LN -> h, hb -------
__global__ __launch_bounds__(256) void ffn_fused(
    const unsigned short* __restrict__ A,   // hb [M][KP]
    const unsigned short* __restrict__ W1t, const float* __restrict__ b1,
    const unsigned short* __restrict__ W2t, const float* __restrict__ b2,
    const float* __restrict__ g, const float* __restrict__ beta,
    float* __restrict__ h, unsigned short* __restrict__ hb, long M) {
  __shared__ unsigned short mid[64 * MLS];  // 33792 B
  __shared__ float2 part[64][5];
  int w = threadIdx.x >> 6;
  int lane = threadIdx.x & 63;
  long wrow = (long)blockIdx.x * 64;
  if (wrow >= M) return;  // uniform over block
  int lrow = lane & 15;
  int kq = lane >> 4;
  // ---- GEMM1 ----
  {
    bfv8 a1[4][6];
#pragma unroll
    for (int rf = 0; rf < 4; ++rf) {
      long ar = wrow + rf * 16 + lrow;
      if (ar >= M) ar = M - 1;
#pragma unroll
      for (int ks = 0; ks < 6; ++ks)
        a1[rf][ks] = *(const bfv8*)(A + ar * (long)KP + kq * 8 + ks * 32);
    }
#pragma unroll
    for (int i = 0; i < 4; ++i) {
      int nt = w * 4 + i;
      int col = nt * 16 + lrow;
      const unsigned short* bp = W1t + (long)col * KP + kq * 8;
      f32x4 c0 = {0, 0, 0, 0}, c1 = {0, 0, 0, 0}, c2 = {0, 0, 0, 0}, c3 = {0, 0, 0, 0};
#pragma unroll
      for (int ks = 0; ks < 6; ++ks) {
        bfv8 b = *(const bfv8*)(bp + ks * 32);
        c0 = __builtin_amdgcn_mfma_f32_16x16x32_bf16(a1[0][ks], b, c0, 0, 0, 0);
        c1 = __builtin_amdgcn_mfma_f32_16x16x32_bf16(a1[1][ks], b, c1, 0, 0, 0);
        c2 = __builtin_amdgcn_mfma_f32_16x16x32_bf16(a1[2][ks], b, c2, 0, 0, 0);
        c3 = __builtin_amdgcn_mfma_f32_16x16x32_bf16(a1[3][ks], b, c3, 0, 0, 0);
      }
      float bv = b1[col];
      f32x4 cc[4] = {c0, c1, c2, c3};
#pragma unroll
      for (int rf = 0; rf < 4; ++rf)
#pragma unroll
        for (int r = 0; r < 4; ++r) {
          float v = fmaxf(cc[rf][r] + bv, 0.f);
          mid[(rf * 16 + kq * 4 + r) * MLS + col] = f2b(v);
        }
    }
  }
  __syncthreads();
  // ---- GEMM2 + LN (A from LDS, K=256 in 2 halves) ----
  f32x4 acc[3][4];
#pragma unroll
  for (int i = 0; i < 3; ++i)
#pragma unroll
    for (int rf = 0; rf < 4; ++rf) acc[i][rf] = f32x4{0.f, 0.f, 0.f, 0.f};
#pragma unroll
  for (int half = 0; half < 2; ++half) {
    bfv8 a2[4][4];
#pragma unroll
    for (int rf = 0; rf < 4; ++rf)
#pragma unroll
      for (int ks = 0; ks < 4; ++ks)
        a2[rf][ks] = *(const bfv8*)(&mid[(rf * 16 + lrow) * MLS + kq * 8 + (half * 4 + ks) * 32]);
#pragma unroll
    for (int i = 0; i < 3; ++i) {
      int nt = w + 4 * i;
      if (nt >= 11) continue;
      int col = nt * 16 + lrow;
      const unsigned short* bp = W2t + (long)col * FFD + kq * 8 + half * 128;
      f32x4 c0 = acc[i][0], c1 = acc[i][1], c2 = acc[i][2], c3 = acc[i][3];
#pragma unroll
      for (int ks = 0; ks < 4; ++ks) {
        bfv8 b = *(const bfv8*)(bp + ks * 32);
        c0 = __builtin_amdgcn_mfma_f32_16x16x32_bf16(a2[0][ks], b, c0, 0, 0, 0);
        c1 = __builtin_amdgcn_mfma_f32_16x16x32_bf16(a2[1][ks], b, c1, 0, 0, 0);
        c2 = __builtin_amdgcn_mfma_f32_16x16x32_bf16(a2[2][ks], b, c2, 0, 0, 0);
        c3 = __builtin_amdgcn_mfma_f32_16x16x32_bf16(a2[3][ks], b, c3, 0, 0, 0);
      }
      acc[i][0] = c0; acc[i][1] = c1; acc[i][2] = c2; acc[i][3] = c3;
    }
  }
  float sum[16], ss[16];
#pragma unroll
  for (int j = 0; j < 16; ++j) { sum[j] = 0.f; ss[j] = 0.f; }
#pragma unroll
  for (int i = 0; i < 3; ++i) {
    int nt = w + 4 * i;
    if (nt >= 11) continue;
    int col = nt * 16 + lrow;
    float bv = b2[col];
#pragma unroll
    for (int rf = 0; rf < 4; ++rf)
#pragma unroll
      for (int r = 0; r < 4; ++r) {
        long row = wrow + rf * 16 + kq * 4 + r;
        long rr = row < M ? row : M - 1;
        float v = acc[i][rf][r] + bv + h[rr * DM + col];
        acc[i][rf][r] = v;
        sum[rf * 4 + r] += v;
        ss[rf * 4 + r] += v * v;
      }
  }
#pragma unroll
  for (int j = 0; j < 16; ++j) {
#pragma unroll
    for (int o = 1; o < 16; o <<= 1) {
      sum[j] += __shfl_xor(sum[j], o);
      ss[j] += __shfl_xor(ss[j], o);
    }
  }
  if (lrow == 0) {
#pragma unroll
    for (int rf = 0; rf < 4; ++rf)
#pragma unroll
      for (int r = 0; r < 4; ++r)
        part[rf * 16 + kq * 4 + r][w] = float2{sum[rf * 4 + r], ss[rf * 4 + r]};
  }
  __syncthreads();
  if (w == 0) {
    float s = 0.f, q = 0.f;
#pragma unroll
    for (int ww = 0; ww < 4; ++ww) {
      float2 p = part[lane][ww];
      s += p.x; q += p.y;
    }
    float mean = s * (1.f / 176.f);
    float var = q * (1.f / 176.f) - mean * mean;
    part[lane][4] = float2{mean, rsqrtf(var + 1e-5f)};
  }
  __syncthreads();
#pragma unroll
  for (int i = 0; i < 3; ++i) {
    int nt = w + 4 * i;
    if (nt >= 11) continue;
    int col = nt * 16 + lrow;
    float gv = g[col], bv2 = beta[col];
#pragma unroll
    for (int rf = 0; rf < 4; ++rf)
#pragma unroll
      for (int r = 0; r < 4; ++r) {
        int lr = rf * 16 + kq * 4 + r;
        long row = wrow + lr;
        if (row >= M) continue;
        float2 st = part[lr][4];
        float y = (acc[i][rf][r] - st.x) * st.y * gv + bv2;
        h[row * DM + col] = y;
        hb[row * KP + col] = f2b(y);
      }
  }
  if (w == 0) {
    long row = wrow + lane;
    if (row < M) {
      ull* zp = (ull*)(hb + row * KP + DM);
      zp[0] = 0ULL; zp[1] = 0ULL; zp[2] = 0ULL; zp[3] = 0ULL;
    }
  }
}

// ---------------- temporal attention (L = 12), LDS-staged per (b, 4-node tile) --
__global__ __launch_bounds__(256) void attn_temporal_lds(
    const unsigned short* __restrict__ qkvh, unsigned short* __restrict__ atth,
    long PS) {
  __shared__ unsigned short ld[4 * 12 * TS];  // 56064 B
  int tile = blockIdx.x % NTILE;
  int b = blockIdx.x / NTILE;   // chunk-local
  int n0 = tile * 4;
  for (int idx = threadIdx.x; idx < 3456; idx += 256) {
    int p = idx / 288;
    int rem = idx % 288;
    int t = rem / 24;
    int rem2 = rem % 24;
    int j = rem2 / 6, e = rem2 % 6;
    uiv4 v = {0, 0, 0, 0};
    int n = n0 + j;
    if (n < NN)
      v = *(const uiv4*)(qkvh + (long)p * PS + ((long)(b * TT + t) * NN + n) * 48 + e * 8);
    *(uiv4*)(&ld[(j * 12 + p) * TS + t * 48 + e * 8]) = v;
  }
  __syncthreads();
  int tid = threadIdx.x;
  if (tid >= 192) return;
  int j = tid / 48, hl = tid % 48;
  int hh = hl / 12, l = hl % 12;
  int n = n0 + j;
  if (n >= NN) return;
  const float scale = 0.15075567228888181f;  // 1/sqrt(44)
  float q[HD];
  const unsigned short* qp = &ld[(j * 12 + hh) * TS + l * 48];
#pragma unroll
  for (int d = 0; d < HD; ++d) q[d] = b2f(qp[d]) * scale;
  float s[TT];
  float mx = -1e30f;
#pragma unroll
  for (int m = 0; m < TT; ++m) {
    const unsigned short* kp = &ld[(j * 12 + 4 + hh) * TS + m * 48];
    float acc = 0.f;
#pragma unroll
    for (int d = 0; d < HD; ++d) acc += q[d] * b2f(kp[d]);
    s[m] = acc;
    mx = fmaxf(mx, acc);
  }
  float den = 0.f;
#pragma unroll
  for (int m = 0; m < TT; ++m) { s[m] = __expf(s[m] - mx); den += s[m]; }
  float inv = 1.f / den;
  float o[HD];
#pragma unroll
  for (int d = 0; d < HD; ++d) o[d] = 0.f;
#pragma unroll
  for (int m = 0; m < TT; ++m) {
    const unsigned short* vp = &ld[(j * 12 + 8 + hh) * TS + m * 48];
    float p = s[m] * inv;
#pragma unroll
    for (int d = 0; d < HD; ++d) o[d] += p * b2f(vp[d]);
  }
  unsigned short* op = atth + (long)hh * PS + ((long)(b * TT + l) * NN + n) * 48;
#pragma unroll
  for (int d = 0; d < HD; d += 2) {
    unsigned u = (unsigned)f2b(o[d]) | ((unsigned)f2b(o[d + 1]) << 16);
    *(unsigned*)(op + d) = u;
  }
  *(ull*)(op + 44) = 0ULL;  // pad
}

// ---------------- spatial attention (L = 307) via MFMA, online softmax ----------
// 512 threads / 8 waves; defer-max (T13). K read directly from global (L1/L2-
// resident, 29 KB/plane) -- no K LDS staging (Common-mistake #7). Q/K high
// k-half (k>=48) zeroed in registers for kq>=2 (was provided by Kl zeros).
#define VTS 332  // Vt row stride (elems)
__global__ __launch_bounds__(512, 2) void attn_spatial_mfma(
    const unsigned short* __restrict__ qkvh, unsigned short* __restrict__ atth,
    long PS) {
  __shared__ unsigned short Vt[48 * VTS];   // 31872 B
  int h = blockIdx.x & 3;
  int bt = blockIdx.x >> 2;
  long tokbase = (long)bt * NN;
  const unsigned short* qbase = qkvh + (long)h * PS + tokbase * 48;
  const unsigned short* kbase = qkvh + (long)(4 + h) * PS + tokbase * 48;
  const unsigned short* vbase = qkvh + (long)(8 + h) * PS + tokbase * 48;
  int tid = threadIdx.x;

  // stage V transposed via 16B loads: Vt[d][m], d=0..47 (44..47 zero from pad)
  for (int task = tid; task < 480; task += 512) {
    int m0 = (task / 6) * 4, c = task % 6;
    const unsigned short* vb = vbase + c * 8;
    uiv4 r0 = {0, 0, 0, 0}, r1 = {0, 0, 0, 0}, r2 = {0, 0, 0, 0}, r3 = {0, 0, 0, 0};
    if (m0 + 0 < NN) r0 = *(const uiv4*)(vb + (long)(m0 + 0) * 48);
    if (m0 + 1 < NN) r1 = *(const uiv4*)(vb + (long)(m0 + 1) * 48);
    if (m0 + 2 < NN) r2 = *(const uiv4*)(vb + (long)(m0 + 2) * 48);
    if (m0 + 3 < NN) r3 = *(const uiv4*)(vb + (long)(m0 + 3) * 48);
#pragma unroll
    for (int j = 0; j < 8; ++j) {
      int w32 = j >> 1, sh = (j & 1) * 16;
      ull o = (ull)((r0[w32] >> sh) & 0xFFFFu) |
              ((ull)((r1[w32] >> sh) & 0xFFFFu) << 16) |
              ((ull)((r2[w32] >> sh) & 0xFFFFu) << 32) |
              ((ull)((r3[w32] >> sh) & 0xFFFFu) << 48);
      *(ull*)(&Vt[(c * 8 + j) * VTS + m0]) = o;
    }
  }
  __syncthreads();

  int w = tid >> 6;          // 0..7
  int lane = tid & 63;
  int lrow = lane & 15;
  int kq = lane >> 4;
  bool hiK = (kq >= 2);      // k in [48,64): both operands zero
  const float kscale = 0.2174944602f;  // 1/sqrt(44)*log2(e)

  bfv8 bz;
#pragma unroll
  for (int j = 0; j < 8; ++j) bz[j] = (__bf16)0.f;

#pragma unroll
  for (int qi = 0; qi < 3; ++qi) {
    int qt = qi * 8 + w;
    if (qt >= 20) break;
    int ql = qt * 16 + lrow;
    int qc = ql < NN ? ql : NN - 1;
    const unsigned short* qrow = qbase + (long)qc * 48;
    bfv8 qb8a = *(const bfv8*)(qrow + kq * 8);
    bfv8 qb8b = hiK ? bz : *(const bfv8*)(qrow + 32 + kq * 8);

    float m_run = -1e30f, den = 0.f;
    f32x4 o0 = {0.f, 0.f, 0.f, 0.f}, o1 = {0.f, 0.f, 0.f, 0.f}, o2 = {0.f, 0.f, 0.f, 0.f};
#pragma unroll
    for (int ct = 0; ct < 20; ++ct) {
      const unsigned short* kp = kbase + (long)(ct * 16 + lrow) * 48;
      bfv8 k8a = *(const bfv8*)(kp + kq * 8);
      bfv8 k8b = hiK ? bz : *(const bfv8*)(kp + 32 + kq * 8);
      f32x4 s = {0.f, 0.f, 0.f, 0.f};
      s = __builtin_amdgcn_mfma_f32_16x16x32_bf16(k8a, qb8a, s, 0, 0, 0);
      s = __builtin_amdgcn_mfma_f32_16x16x32_bf16(k8b, qb8b, s, 0, 0, 0);
#pragma unroll
      for (int r = 0; r < 4; ++r) {
        float v = s[r] * kscale;
        if (ct == 19 && (kq * 4 + r) >= 3) v = -1e30f;  // m >= 307 (masks OOR rows)
        s[r] = v;
      }
      float smax = fmaxf(fmaxf(s[0], s[1]), fmaxf(s[2], s[3]));
      if (!__all(smax <= m_run + 8.f)) {
        smax = fmaxf(smax, __shfl_xor(smax, 16));
        smax = fmaxf(smax, __shfl_xor(smax, 32));
        float m_new = fmaxf(m_run, smax);
        float corr = exp2f(m_run - m_new);
        m_run = m_new;
        den *= corr;
        o0 = o0 * corr;
        o1 = o1 * corr;
        o2 = o2 * corr;
      }
      float p0 = exp2f(s[0] - m_run);
      float p1 = exp2f(s[1] - m_run);
      float p2 = exp2f(s[2] - m_run);
      float p3 = exp2f(s[3] - m_run);
      den += (p0 + p1) + (p2 + p3);
      sv4 pb = {(short)f2b(p0), (short)f2b(p1), (short)f2b(p2), (short)f2b(p3)};
      int mb = ct * 16 + kq * 4;
      sv4 a0 = *(const sv4*)(&Vt[(0 * 16 + lrow) * VTS + mb]);
      sv4 a1 = *(const sv4*)(&Vt[(1 * 16 + lrow) * VTS + mb]);
      sv4 a2 = *(const sv4*)(&Vt[(2 * 16 + lrow) * VTS + mb]);
      o0 = mfma16x16x16bf(a0, pb, o0);
      o1 = mfma16x16x16bf(a1, pb, o1);
      o2 = mfma16x16x16bf(a2, pb, o2);
    }
    den += __shfl_xor(den, 16);
    den += __shfl_xor(den, 32);
    float inv = 1.f / den;

    if (ql < NN) {
      unsigned short* dst = atth + (long)h * PS + (tokbase + ql) * 48;
      int db = kq * 4;
      {
        ull u = (ull)f2b(o0[0] * inv) | ((ull)f2b(o0[1] * inv) << 16) |
                ((ull)f2b(o0[2] * inv) << 32) | ((ull)f2b(o0[3] * inv) << 48);
        *(ull*)(dst + db) = u;
      }
      {
        ull u = (ull)f2b(o1[0] * inv) | ((ull)f2b(o1[1] * inv) << 16) |
                ((ull)f2b(o1[2] * inv) << 32) | ((ull)f2b(o1[3] * inv) << 48);
        *(ull*)(dst + 16 + db) = u;
      }
      if (db < 12) {
        ull u = (ull)f2b(o2[0] * inv) | ((ull)f2b(o2[1] * inv) << 16) |
                ((ull)f2b(o2[2] * inv) << 32) | ((ull)f2b(o2[3] * inv) << 48);
        *(ull*)(dst + 32 + db) = u;
      } else {
        *(ull*)(dst + 44) = 0ULL;
      }
    }
  }
}

// ---------------- output projection (chunk of nb batches starting at b0) ----------
__global__ __launch_bounds__(64) void out_kernel(
    const float* __restrict__ h, const float* __restrict__ Wout,
    const float* __restrict__ bout, float* __restrict__ out, int b0) {
  int bn = blockIdx.x;  // chunk-local b*307+n
  int n = bn % NN, bl = bn / NN;
  int b = b0 + bl;
  int lane = threadIdx.x;
  float acc[TT];
#pragma unroll
  for (int j = 0; j < TT; ++j) acc[j] = 0.f;
  for (int k = lane; k < TT * DM; k += 64) {
    int t = k / DM, d = k % DM;
    float a = h[((long)(bl * TT + t) * NN + n) * DM + d];
    const float* wp = Wout + (long)k * TT;
#pragma unroll
    for (int j = 0; j < TT; ++j) acc[j] += a * wp[j];
  }
#pragma unroll
  for (int j = 0; j < TT; ++j)
    for (int o = 32; o > 0; o >>= 1) acc[j] += __shfl_xor(acc[j], o);
  if (lane < TT) out[((long)b * TT + lane) * NN + n] = acc[lane] + bout[lane];
}

// ---------------- launch ----------------
// Input order = setup_inputs() dict insertion order:
//  0 x, 1 W_in, 2 b_in, 3 tod_emb, 4 dow_emb, 5 node_emb, 6 adp_emb,
//  7 Wout, 8 bout,
//  9 tWq..24 tB2 (temporal block), 25 sWq..40 sB2 (spatial block)
extern "C" void kernel_launch(void* const* d_in, const int* in_sizes, int n_in,
                              void* d_out, int out_size, void* d_ws, size_t ws_size,
                              hipStream_t stream) {
  char* ws = (char*)d_ws;
  unsigned short* wbase = (unsigned short*)ws;           // 2,752,512 B
  float* bqkv = (float*)(ws + 2752512L);                 //    12,672 B
  char* dyn = ws + 2765184L;

  // per-token bytes: h(704) + hb(384) + qkvh(1152) + atth(384)
  const long per_tok = 2624;
  int nb = 0;
  for (int c = 32; c >= 1; --c) {
    if (2765184L + (long)c * TPB * per_tok <= (long)ws_size) { nb = c; break; }
  }
  if (nb == 0) return;

  const long Mal = (long)nb * TPB;
  const long PS = Mal * 48;  // plane stride (elems)
  float* h = (float*)dyn;
  unsigned short* hb = (unsigned short*)(dyn + Mal * 704);
  unsigned short* qkvh = (unsigned short*)(dyn + Mal * 1088);
  unsigned short* atth = (unsigned short*)(dyn + Mal * 2240);

#define DF(i) ((const float*)d_in[i])

  prep_weights<<<dim3(396, 6, 4), 256, 0, stream>>>(
      DF(9), DF(11), DF(13), DF(15), DF(17), DF(19),
      DF(25), DF(27), DF(29), DF(31), DF(33), DF(35),
      DF(10), DF(12), DF(14), DF(26), DF(28), DF(30), wbase, bqkv);

  for (int b0 = 0; b0 < BB; b0 += nb) {
    int nb_cur = (BB - b0 < nb) ? (BB - b0) : nb;
    const long Mc = (long)nb_cur * TPB;
    int gx = (int)((Mc + 255) / 256);
    int gx64 = (int)((Mc + 63) / 64);

    embed_kernel<<<(int)((Mc * KP + 255) / 256), 256, 0, stream>>>(
        DF(0), DF(1), DF(2), DF(3), DF(4), DF(5), DF(6), h, hb,
        (long)b0 * TPB, Mc);

    for (int l = 0; l < 6; ++l) {
      int base = (l < 3) ? 9 : 25;
      int li = l % 3;
      const unsigned short* wl = wbase + (long)l * 229376;
      const unsigned short* Wqkv = wl;
      const unsigned short* Wo = wl + 101376;
      const unsigned short* W1 = wl + 135168;
      const unsigned short* W2 = wl + 184320;
      const float* bo = DF(base + 7) + li * 176;
      const float* b1 = DF(base + 9) + li * 256;
      const float* b2 = DF(base + 11) + li * 176;
      const float* g1 = DF(base + 12) + li * 176;
      const float* B1 = DF(base + 13) + li * 176;
      const float* g2 = DF(base + 14) + li * 176;
      const float* B2 = DF(base + 15) + li * 176;

      gemm_bias<6, false, true, true><<<dim3(gx, 3), 256, 0, stream>>>(
          hb, KP, Wqkv, bqkv + l * 528, qkvh, 0, Mc, 528, 11, PS);

      if (l < 3) {
        attn_temporal_lds<<<nb_cur * NTILE, 256, 0, stream>>>(qkvh, atth, PS);
      } else {
        attn_spatial_mfma<<<nb_cur * TT * NH, 512, 0, stream>>>(qkvh, atth, PS);
      }

      gemm_ln_fused<6, true><<<gx64, 256, 0, stream>>>(
          atth, KP, Wo, bo, g1, B1, h, hb, Mc, PS);

      ffn_fused<<<gx64, 256, 0, stream>>>(
          hb, W1, b1, W2, b2, g2, B2, h, hb, Mc);
    }

    out_kernel<<<nb_cur * NN, 64, 0, stream>>>(h, DF(7), DF(8), (float*)d_out, b0);
  }
#undef DF
}